// Round 15
// baseline (311.607 us; speedup 1.0000x reference)
//
#include <hip/hip_runtime.h>

#define BB 4
#define NN 8192
#define QW 16         // queries per wave = MFMA N
#define CAP 64        // survivor capacity per query
#define SLACK 4e-3f   // > 2*eps(bf16 hi/lo filter vs exact d~)
#define PD 16         // pipeline depth (tiles in flight)

typedef unsigned long long u64;
typedef unsigned int u32;
typedef __attribute__((ext_vector_type(8))) short s16x8;   // 8 bf16 (4 VGPRs)
typedef __attribute__((ext_vector_type(4))) float f32x4;

__device__ __forceinline__ u64 shfl_xor_u64(u64 v, int m) {
  u32 lo = (u32)v, hi = (u32)(v >> 32);
  lo = (u32)__shfl_xor((int)lo, m, 64);
  hi = (u32)__shfl_xor((int)hi, m, 64);
  return ((u64)hi << 32) | lo;
}
__device__ __forceinline__ u64 min_u64(u64 a, u64 b) { return a < b ? a : b; }
__device__ __forceinline__ float rfl(float x) {
  return __int_as_float(__builtin_amdgcn_readfirstlane(__float_as_int(x)));
}
// float -> bf16 bits, round-to-nearest-even
__device__ __forceinline__ u32 fb(float f) {
  u32 u = __float_as_uint(f);
  return (u + 0x7FFFu + ((u >> 16) & 1u)) >> 16;
}
__device__ __forceinline__ float bf2f(u32 h) { return __uint_as_float(h << 16); }

// np-exact distance (bit-matches reference; fma(-2,..) == t-2*inner exactly)
__device__ __forceinline__ float dist_exact(float qx, float qy, float qz, float qw,
                                            float cx, float cy, float cz, float cw) {
#pragma clang fp contract(off)
  float inner = qx * cx;
  inner = inner + qy * cy;
  inner = inner + qz * cz;
  float tt = qw + cw;
  return __builtin_fmaf(-2.0f, inner, tt);
}

// ---- fused: zmat (blocks 0..1023) + coords prep (blocks 1024..1151) ----
__global__ void fused_prep_zmat(const float* __restrict__ x, const float* __restrict__ W,
                                const float* __restrict__ coords,
                                float* __restrict__ z, float4* __restrict__ c4p,
                                u32* __restrict__ Ap, float* __restrict__ ycoords) {
#pragma clang fp contract(off)
  __shared__ float Ws[64 * 65];
  __shared__ float xs[64 * 32];
  int t = threadIdx.x;
  if (blockIdx.x < 1024) {
    int blk = blockIdx.x;
    int b = blk >> 8;
    int j0 = (blk & 255) * 32;
    for (int r = t; r < 4096; r += 256) Ws[(r >> 6) * 65 + (r & 63)] = W[r];
    const float* xb = x + (size_t)b * 64 * NN;
    for (int r = 0; r < 8; ++r) {
      int idx = t + r * 256;
      int c = idx >> 5, j = idx & 31;
      xs[c * 32 + j] = xb[(size_t)c * NN + j0 + j];
    }
    __syncthreads();
    int o = t & 63, jb = (t >> 6) * 8;
    float acc[8];
#pragma unroll
    for (int m = 0; m < 8; ++m) acc[m] = 0.f;
    for (int c = 0; c < 64; ++c) {
      float w = Ws[o * 65 + c];
#pragma unroll
      for (int m = 0; m < 8; ++m) acc[m] = __builtin_fmaf(w, xs[c * 32 + jb + m], acc[m]);
    }
#pragma unroll
    for (int m = 0; m < 8; ++m)
      z[((size_t)b * NN + j0 + jb + m) * 64 + o] = acc[m];
  } else {
    int t2 = (blockIdx.x - 1024) * 256 + t;   // [0, B*N) candidates
    int b = t2 >> 13;
    int i = t2 & (NN - 1);
    const float* cb = coords + (size_t)b * 3 * NN;
    float cx = cb[i];
    float cy = cb[NN + i];
    float cz = cb[2 * NN + i];
    float sq = (cx * cx + cy * cy) + cz * cz;   // np-exact sequential fp32
    float4 v; v.x = -2.0f * cx; v.y = -2.0f * cy; v.z = -2.0f * cz; v.w = sq;
    c4p[t2] = v;
    // bf16 hi/lo split for the MFMA A-plane (raw coords + sq)
    u32 hx = fb(cx); u32 lx = fb(cx - bf2f(hx));
    u32 hy = fb(cy); u32 ly = fb(cy - bf2f(hy));
    u32 hz = fb(cz); u32 lz = fb(cz - bf2f(hz));
    u32 hq = fb(sq); u32 lq = fb(sq - bf2f(hq));
    uint4 w0, w1;
    w0.x = hx | (lx << 16);   // slots 0,1
    w0.y = hx | (hy << 16);   // slots 2,3
    w0.z = ly | (hy << 16);   // slots 4,5
    w0.w = hz | (lz << 16);   // slots 6,7
    w1.x = hz | (hq << 16);   // slots 8,9
    w1.y = lq;                // slots 10,11
    w1.z = 0; w1.w = 0;       // slots 12..15
    uint4* ap4 = (uint4*)(Ap + (size_t)t2 * 8);
    ap4[0] = w0; ap4[1] = w1;
#pragma unroll
    for (int r = 0; r < 3; ++r)
      ycoords[r * (BB * NN) + t2] = coords[r * (BB * NN) + t2];
  }
}

// ---- KNN: 1 wave/block, 16 queries; MFMA filter, 16-deep pipelined feed ----
// R13: 1-deep -> MfmaUtil 5%. R14: 8-deep -> 9%, duty 37%, VGPR only 44.
// R15: 16-deep (spend the idle registers on load slack; ~320cyc >= L2 latency).
__global__ void __launch_bounds__(64, 4) knn_gather(const float4* __restrict__ c4p,
                                                    const u32* __restrict__ Ap,
                                                    const float* __restrict__ z,
                                                    float* __restrict__ y) {
  __shared__ u32 buf[1024];       // 4KB: bufB(128 u32) -> Tsc(512 f32) -> survj[16][64]
  __shared__ int scnt[16];
  __shared__ int sidx[16][16];
  __shared__ float ys[64 * 17];
  int lane = threadIdx.x;         // 64-thread block = 1 wave
  int qbase = blockIdx.x * QW;
  int b = qbase >> 13;
  int i0 = qbase & (NN - 1);
  const float4* cp4 = c4p + (size_t)b * NN;
  const u32* Ab = Ap + (size_t)b * NN * 8;

  if (lane < 16) scnt[lane] = 0;

  // ---- build B-frag table (queries, hi/lo of -2q) in LDS, then load frags ----
  if (lane < 16) {
    float4 qv = cp4[i0 + lane];   // (-2x,-2y,-2z,sq)
    u32 hpx = fb(qv.x); u32 lpx = fb(qv.x - bf2f(hpx));
    u32 hpy = fb(qv.y); u32 lpy = fb(qv.y - bf2f(hpy));
    u32 hpz = fb(qv.z); u32 lpz = fb(qv.z - bf2f(hpz));
    const u32 ONE = 0x3F80u;
    buf[lane * 8 + 0] = hpx | (hpx << 16);  // slots 0,1
    buf[lane * 8 + 1] = lpx | (hpy << 16);  // slots 2,3
    buf[lane * 8 + 2] = hpy | (lpy << 16);  // slots 4,5
    buf[lane * 8 + 3] = hpz | (hpz << 16);  // slots 6,7
    buf[lane * 8 + 4] = lpz | (ONE << 16);  // slots 8,9
    buf[lane * 8 + 5] = ONE;                // slots 10,11
    buf[lane * 8 + 6] = 0;
    buf[lane * 8 + 7] = 0;
  }
  int g = lane >> 4, qcol = lane & 15;
  union { uint4 u; s16x8 s; } bfr;
  bfr.u = make_uint4(0, 0, 0, 0);
  if (g < 2) {
    bfr.u.x = buf[qcol * 8 + g * 4 + 0];
    bfr.u.y = buf[qcol * 8 + g * 4 + 1];
    bfr.u.z = buf[qcol * 8 + g * 4 + 2];
    bfr.u.w = buf[qcol * 8 + g * 4 + 3];
  }
  s16x8 bfrag = bfr.s;
  f32x4 zeroC = {0.f, 0.f, 0.f, 0.f};

  int laneoff = (lane & 15) * 8 + (lane >> 4) * 4;   // u32 units (valid for lane<32)
  bool aload = lane < 32;

  // ---- pass A: 16-deep pipelined MFMA scan, min-fold into 8 regs ----
  float mi[8];
#pragma unroll
  for (int m = 0; m < 8; ++m) mi[m] = 3.402823466e+38f;

  uint4 abuf[PD];
#pragma unroll
  for (int p = 0; p < PD; ++p) {
    abuf[p] = make_uint4(0, 0, 0, 0);
    if (aload) abuf[p] = *(const uint4*)(Ab + p * 128 + laneoff);
  }
#pragma unroll 1
  for (int tg = 0; tg < NN / 16 / PD; ++tg) {
#pragma unroll
    for (int p = 0; p < PD; ++p) {
      union { uint4 u; s16x8 s; } af; af.u = abuf[p];
      f32x4 D = __builtin_amdgcn_mfma_f32_16x16x32_bf16(af.s, bfrag, zeroC, 0, 0, 0);
      int tn = tg * PD + p + PD;                 // wave-uniform (scalar clamp)
      if (tn > NN / 16 - 1) tn = NN / 16 - 1;
      if (aload) abuf[p] = *(const uint4*)(Ab + tn * 128 + laneoff);
      // phase (tg*PD+p)&3 == p&3: chunk partition identical to R13 (verified)
      mi[(p & 3) * 2 + 0] = fminf(fminf(mi[(p & 3) * 2 + 0], D.x), D.y);
      mi[(p & 3) * 2 + 1] = fminf(fminf(mi[(p & 3) * 2 + 1], D.z), D.w);
    }
  }

  // re-prime pipeline for pass B NOW (latency hidden under threshold bitonics)
#pragma unroll
  for (int p = 0; p < PD; ++p)
    if (aload) abuf[p] = *(const uint4*)(Ab + p * 128 + laneoff);

  // ---- 32 chunk-minima/query -> T = 16th smallest (dual 32-lane bitonics) ----
  float* Tsc = (float*)buf;                  // overwrites bufB (done)
#pragma unroll
  for (int p = 0; p < 4; ++p) {
    Tsc[qcol * 32 + g * 8 + p * 2 + 0] = mi[p * 2 + 0];
    Tsc[qcol * 32 + g * 8 + p * 2 + 1] = mi[p * 2 + 1];
  }
  float Tmy = 0.f;
  int ll = lane & 31;
#pragma unroll 1
  for (int s = 0; s < 8; ++s) {
    float v = Tsc[((s << 1) | (lane >> 5)) * 32 + ll];
#pragma unroll
    for (int k = 2; k <= 32; k <<= 1) {
#pragma unroll
      for (int jm = k >> 1; jm >= 1; jm >>= 1) {
        float o = __shfl_xor(v, jm, 64);     // masks < 32: stays within half
        bool keepmin = ((ll & jm) == 0) == ((ll & k) == 0);
        v = keepmin ? fminf(v, o) : fmaxf(v, o);
      }
    }
    float tlow = __shfl(v, 15, 64);          // 16th smallest, lower half
    float thigh = __shfl(v, 47, 64);         // 16th smallest, upper half
    if (qcol == 2 * s)     Tmy = tlow;
    if (qcol == 2 * s + 1) Tmy = thigh;
  }
  Tmy += SLACK;

  // ---- pass B: identical pipelined scan, fire survivor indices ----
  u32* survj = buf;                          // overwrites Tsc (done)
#pragma unroll 1
  for (int tg = 0; tg < NN / 16 / PD; ++tg) {
#pragma unroll
    for (int p = 0; p < PD; ++p) {
      union { uint4 u; s16x8 s; } af; af.u = abuf[p];
      f32x4 D = __builtin_amdgcn_mfma_f32_16x16x32_bf16(af.s, bfrag, zeroC, 0, 0, 0);
      int tile = tg * PD + p;
      int tn = tile + PD;                        // wave-uniform (scalar clamp)
      if (tn > NN / 16 - 1) tn = NN / 16 - 1;
      if (aload) abuf[p] = *(const uint4*)(Ab + tn * 128 + laneoff);
      float dmin = fminf(fminf(D.x, D.y), fminf(D.z, D.w));
      if (dmin <= Tmy) {                     // rare wave-divergent gate
        int jb = tile * 16 + (lane >> 4) * 4;
#pragma unroll
        for (int r = 0; r < 4; ++r) {
          float dv = (r == 0) ? D.x : (r == 1) ? D.y : (r == 2) ? D.z : D.w;
          if (dv <= Tmy) {
            int pos = atomicAdd(&scnt[qcol], 1);
            if (pos < CAP) survj[qcol * CAP + pos] = (u32)(jb + r);
          }
        }
      }
    }
  }

  // ---- epilogue: np-exact keys, u64 bitonic top-16, gather z + max ----
  const float* zb = z + (size_t)b * NN * 64;
#pragma unroll 1
  for (int q = 0; q < 16; ++q) {
    int n = scnt[q]; if (n > CAP) n = CAP;
    float4 qv = cp4[i0 + q];                 // uniform load
    float qxs = rfl(-0.5f * qv.x), qys = rfl(-0.5f * qv.y);
    float qzs = rfl(-0.5f * qv.z), qws = rfl(qv.w);
    u64 v = ~0ull;
    if (lane < n) {
      int j = (int)survj[q * CAP + lane];
      float4 cj = cp4[j];
      float de = dist_exact(qxs, qys, qzs, qws,
                            -0.5f * cj.x, -0.5f * cj.y, -0.5f * cj.z, cj.w);
      u32 f = __float_as_uint(de);
      u32 m32 = f ^ ((u32)(((int)f) >> 31) | 0x80000000u);
      v = ((u64)m32 << 32) | (u32)j;
    }
#pragma unroll
    for (int k = 2; k <= 64; k <<= 1) {
#pragma unroll
      for (int jm = k >> 1; jm >= 1; jm >>= 1) {
        u64 o = shfl_xor_u64(v, jm);
        bool keepmin = ((lane & jm) == 0) == ((lane & k) == 0);
        u64 mn = min_u64(v, o);
        u64 mx = (v < o) ? o : v;
        v = keepmin ? mn : mx;
      }
    }
    if (lane < 16) sidx[q][lane] = (int)(v & 0xFFFFFFFFull);
  }
#pragma unroll 1
  for (int q = 0; q < 16; ++q) {
    const int* id = sidx[q];                 // wave-local, program-order safe
    float m = -3.402823466e+38f;
#pragma unroll
    for (int k = 0; k < 16; ++k)
      m = fmaxf(m, zb[(size_t)id[k] * 64 + lane]);   // coalesced 256B row
    ys[lane * 17 + q] = m;
  }
#pragma unroll
  for (int r = 0; r < 16; ++r) {
    int e = r * 64 + lane;
    int o = e >> 4, qq = e & 15;
    y[((size_t)b * 64 + o) * NN + i0 + qq] = ys[o * 17 + qq];
  }
}

extern "C" void kernel_launch(void* const* d_in, const int* in_sizes, int n_in,
                              void* d_out, int out_size, void* d_ws, size_t ws_size,
                              hipStream_t stream) {
  const float* x      = (const float*)d_in[0];   // [B,64,N]
  const float* coords = (const float*)d_in[1];   // [B,3,N]
  const float* W      = (const float*)d_in[2];   // [64,64]
  float* y = (float*)d_out;                      // [B,64,N] then coords

  char* ws = (char*)d_ws;
  float4* c4p = (float4*)ws;                     // 512 KB
  float*  z   = (float*)(ws + (1u << 20));       // 8 MB @ 1MB
  u32*    Ap  = (u32*)(ws + (9u << 20));         // 1 MB bf16 A-plane @ 9MB

  float* ycoords = y + (size_t)BB * 64 * NN;

  fused_prep_zmat<<<1024 + 128, 256, 0, stream>>>(x, W, coords, z, c4p, Ap, ycoords);
  knn_gather<<<BB * NN / QW, 64, 0, stream>>>(c4p, Ap, z, y);
}

// Round 16
// 179.748 us; speedup vs baseline: 1.7336x; 1.7336x over previous
//
#include <hip/hip_runtime.h>

#define BB 4
#define NN 8192
#define CAP 64        // survivor capacity per query
#define SLACK 4e-3f   // > 2*eps(bf16 hi/lo filter vs exact d~)
#define PD 8          // pipeline depth (R14-proven; R15: deeper spills)

typedef unsigned long long u64;
typedef unsigned int u32;
typedef __attribute__((ext_vector_type(8))) short s16x8;   // 8 bf16 (4 VGPRs)
typedef __attribute__((ext_vector_type(4))) float f32x4;

__device__ __forceinline__ u64 shfl_xor_u64(u64 v, int m) {
  u32 lo = (u32)v, hi = (u32)(v >> 32);
  lo = (u32)__shfl_xor((int)lo, m, 64);
  hi = (u32)__shfl_xor((int)hi, m, 64);
  return ((u64)hi << 32) | lo;
}
__device__ __forceinline__ u64 min_u64(u64 a, u64 b) { return a < b ? a : b; }
__device__ __forceinline__ float rfl(float x) {
  return __int_as_float(__builtin_amdgcn_readfirstlane(__float_as_int(x)));
}
// float -> bf16 bits, round-to-nearest-even
__device__ __forceinline__ u32 fb(float f) {
  u32 u = __float_as_uint(f);
  return (u + 0x7FFFu + ((u >> 16) & 1u)) >> 16;
}
__device__ __forceinline__ float bf2f(u32 h) { return __uint_as_float(h << 16); }

// np-exact distance (bit-matches reference; fma(-2,..) == t-2*inner exactly)
__device__ __forceinline__ float dist_exact(float qx, float qy, float qz, float qw,
                                            float cx, float cy, float cz, float cw) {
#pragma clang fp contract(off)
  float inner = qx * cx;
  inner = inner + qy * cy;
  inner = inner + qz * cz;
  float tt = qw + cw;
  return __builtin_fmaf(-2.0f, inner, tt);
}

// ---- fused: zmat (blocks 0..1023) + coords prep (blocks 1024..1151) — unchanged ----
__global__ void fused_prep_zmat(const float* __restrict__ x, const float* __restrict__ W,
                                const float* __restrict__ coords,
                                float* __restrict__ z, float4* __restrict__ c4p,
                                u32* __restrict__ Ap, float* __restrict__ ycoords) {
#pragma clang fp contract(off)
  __shared__ float Ws[64 * 65];
  __shared__ float xs[64 * 32];
  int t = threadIdx.x;
  if (blockIdx.x < 1024) {
    int blk = blockIdx.x;
    int b = blk >> 8;
    int j0 = (blk & 255) * 32;
    for (int r = t; r < 4096; r += 256) Ws[(r >> 6) * 65 + (r & 63)] = W[r];
    const float* xb = x + (size_t)b * 64 * NN;
    for (int r = 0; r < 8; ++r) {
      int idx = t + r * 256;
      int c = idx >> 5, j = idx & 31;
      xs[c * 32 + j] = xb[(size_t)c * NN + j0 + j];
    }
    __syncthreads();
    int o = t & 63, jb = (t >> 6) * 8;
    float acc[8];
#pragma unroll
    for (int m = 0; m < 8; ++m) acc[m] = 0.f;
    for (int c = 0; c < 64; ++c) {
      float w = Ws[o * 65 + c];
#pragma unroll
      for (int m = 0; m < 8; ++m) acc[m] = __builtin_fmaf(w, xs[c * 32 + jb + m], acc[m]);
    }
#pragma unroll
    for (int m = 0; m < 8; ++m)
      z[((size_t)b * NN + j0 + jb + m) * 64 + o] = acc[m];
  } else {
    int t2 = (blockIdx.x - 1024) * 256 + t;   // [0, B*N) candidates
    int b = t2 >> 13;
    int i = t2 & (NN - 1);
    const float* cb = coords + (size_t)b * 3 * NN;
    float cx = cb[i];
    float cy = cb[NN + i];
    float cz = cb[2 * NN + i];
    float sq = (cx * cx + cy * cy) + cz * cz;   // np-exact sequential fp32
    float4 v; v.x = -2.0f * cx; v.y = -2.0f * cy; v.z = -2.0f * cz; v.w = sq;
    c4p[t2] = v;
    u32 hx = fb(cx); u32 lx = fb(cx - bf2f(hx));
    u32 hy = fb(cy); u32 ly = fb(cy - bf2f(hy));
    u32 hz = fb(cz); u32 lz = fb(cz - bf2f(hz));
    u32 hq = fb(sq); u32 lq = fb(sq - bf2f(hq));
    uint4 w0, w1;
    w0.x = hx | (lx << 16);
    w0.y = hx | (hy << 16);
    w0.z = ly | (hy << 16);
    w0.w = hz | (lz << 16);
    w1.x = hz | (hq << 16);
    w1.y = lq;
    w1.z = 0; w1.w = 0;
    uint4* ap4 = (uint4*)(Ap + (size_t)t2 * 8);
    ap4[0] = w0; ap4[1] = w1;
#pragma unroll
    for (int r = 0; r < 3; ++r)
      ycoords[r * (BB * NN) + t2] = coords[r * (BB * NN) + t2];
  }
}

// ---- KNN: 256-thr block = 2 query-groups x 2 candidate-halves; MFMA filter ----
// R14: 1-wave blocks -> 2 waves/SIMD, duty 37%. R16: split x2 -> 4 waves/SIMD.
__global__ void __launch_bounds__(256, 4) knn_gather(const float4* __restrict__ c4p,
                                                     const u32* __restrict__ Ap,
                                                     const float* __restrict__ z,
                                                     float* __restrict__ y) {
  __shared__ u32 bshare[2][128];     // B-frag staging per query-group (1 KB)
  __shared__ float Tsc4[4][512];     // per-wave 16q x 32 chunk-minima (8 KB)
  __shared__ float Thalf[32][2];     // per-query per-half thresholds
  __shared__ int scnt[32];
  __shared__ u32 survj[32][CAP];     // 8 KB, shared across the 2 half-waves
  __shared__ int sidx[32][16];       // 2 KB
  __shared__ float ys[64][33];       // 8.25 KB
  int t = threadIdx.x;
  int w = t >> 6, lane = t & 63;
  int h = w & 1, qg = w >> 1;        // candidate half, query group
  int qb_blk = blockIdx.x * 32;      // 32 queries per block
  int b = qb_blk >> 13;
  int i0b = qb_blk & (NN - 1);
  const float4* cp4 = c4p + (size_t)b * NN;
  const u32* Ab = Ap + (size_t)b * NN * 8;

  if (t < 32) scnt[t] = 0;

  // ---- B-frag table for this wave's 16 queries (both h-waves write same data) ----
  if (lane < 16) {
    float4 qv = cp4[i0b + qg * 16 + lane];   // (-2x,-2y,-2z,sq)
    u32 hpx = fb(qv.x); u32 lpx = fb(qv.x - bf2f(hpx));
    u32 hpy = fb(qv.y); u32 lpy = fb(qv.y - bf2f(hpy));
    u32 hpz = fb(qv.z); u32 lpz = fb(qv.z - bf2f(hpz));
    const u32 ONE = 0x3F80u;
    bshare[qg][lane * 8 + 0] = hpx | (hpx << 16);
    bshare[qg][lane * 8 + 1] = lpx | (hpy << 16);
    bshare[qg][lane * 8 + 2] = hpy | (lpy << 16);
    bshare[qg][lane * 8 + 3] = hpz | (hpz << 16);
    bshare[qg][lane * 8 + 4] = lpz | (ONE << 16);
    bshare[qg][lane * 8 + 5] = ONE;
    bshare[qg][lane * 8 + 6] = 0;
    bshare[qg][lane * 8 + 7] = 0;
  }
  __syncthreads();                   // covers scnt init + bshare visibility

  int lg = lane >> 4, qcol = lane & 15;   // lane-group, query column
  union { uint4 u; s16x8 s; } bfr;
  bfr.u = make_uint4(0, 0, 0, 0);
  if (lg < 2) {
    bfr.u.x = bshare[qg][qcol * 8 + lg * 4 + 0];
    bfr.u.y = bshare[qg][qcol * 8 + lg * 4 + 1];
    bfr.u.z = bshare[qg][qcol * 8 + lg * 4 + 2];
    bfr.u.w = bshare[qg][qcol * 8 + lg * 4 + 3];
  }
  s16x8 bfrag = bfr.s;
  f32x4 zeroC = {0.f, 0.f, 0.f, 0.f};

  int laneoff = qcol * 8 + lg * 4;        // u32 units (valid for lane<32)
  bool aload = lane < 32;
  int tb = h * 256;                       // this wave's first tile (256 tiles/half)

  // ---- pass A: PD-deep pipelined MFMA scan of own half, min-fold 8 regs ----
  float mi[8];
#pragma unroll
  for (int m = 0; m < 8; ++m) mi[m] = 3.402823466e+38f;

  uint4 abuf[PD];
#pragma unroll
  for (int p = 0; p < PD; ++p) {
    abuf[p] = make_uint4(0, 0, 0, 0);
    if (aload) abuf[p] = *(const uint4*)(Ab + (tb + p) * 128 + laneoff);
  }
#pragma unroll 1
  for (int tg = 0; tg < 256 / PD; ++tg) {
#pragma unroll
    for (int p = 0; p < PD; ++p) {
      union { uint4 u; s16x8 s; } af; af.u = abuf[p];
      f32x4 D = __builtin_amdgcn_mfma_f32_16x16x32_bf16(af.s, bfrag, zeroC, 0, 0, 0);
      int tn = tg * PD + p + PD;               // local tile, wave-uniform clamp
      if (tn > 255) tn = 255;
      if (aload) abuf[p] = *(const uint4*)(Ab + (tb + tn) * 128 + laneoff);
      mi[(p & 3) * 2 + 0] = fminf(fminf(mi[(p & 3) * 2 + 0], D.x), D.y);
      mi[(p & 3) * 2 + 1] = fminf(fminf(mi[(p & 3) * 2 + 1], D.z), D.w);
    }
  }

  // re-prime pipeline for pass B (latency hidden under threshold work)
#pragma unroll
  for (int p = 0; p < PD; ++p)
    if (aload) abuf[p] = *(const uint4*)(Ab + (tb + p) * 128 + laneoff);

  // ---- per-half threshold: 16th smallest of 32 chunk-minima (dual 32-lane sorts) ----
  float* Tsc = Tsc4[w];
#pragma unroll
  for (int p = 0; p < 4; ++p) {
    Tsc[qcol * 32 + lg * 8 + p * 2 + 0] = mi[p * 2 + 0];
    Tsc[qcol * 32 + lg * 8 + p * 2 + 1] = mi[p * 2 + 1];
  }
  int ll = lane & 31;
#pragma unroll 1
  for (int s = 0; s < 8; ++s) {
    float v = Tsc[((s << 1) | (lane >> 5)) * 32 + ll];
#pragma unroll
    for (int k = 2; k <= 32; k <<= 1) {
#pragma unroll
      for (int jm = k >> 1; jm >= 1; jm >>= 1) {
        float o = __shfl_xor(v, jm, 64);     // masks < 32: stays within half
        bool keepmin = ((ll & jm) == 0) == ((ll & k) == 0);
        v = keepmin ? fminf(v, o) : fmaxf(v, o);
      }
    }
    float tlow = __shfl(v, 15, 64);          // full-wave shuffles (R6 lesson)
    float thigh = __shfl(v, 47, 64);
    if (lane == 0) {
      Thalf[qg * 16 + 2 * s + 0][h] = tlow;
      Thalf[qg * 16 + 2 * s + 1][h] = thigh;
    }
  }
  __syncthreads();                           // thresholds visible across halves

  // combined threshold: D16 <= min(T_h0, T_h1); slack covers bf16 filter error
  float Tq = fminf(Thalf[qg * 16 + qcol][0], Thalf[qg * 16 + qcol][1]) + SLACK;

  // ---- pass B: identical pipelined scan of own half, fire survivor indices ----
#pragma unroll 1
  for (int tg = 0; tg < 256 / PD; ++tg) {
#pragma unroll
    for (int p = 0; p < PD; ++p) {
      union { uint4 u; s16x8 s; } af; af.u = abuf[p];
      f32x4 D = __builtin_amdgcn_mfma_f32_16x16x32_bf16(af.s, bfrag, zeroC, 0, 0, 0);
      int tile = tg * PD + p;
      int tn = tile + PD;
      if (tn > 255) tn = 255;
      if (aload) abuf[p] = *(const uint4*)(Ab + (tb + tn) * 128 + laneoff);
      float dmin = fminf(fminf(D.x, D.y), fminf(D.z, D.w));
      if (dmin <= Tq) {                      // rare wave-divergent gate
        int jb = (tb + tile) * 16 + lg * 4;  // C-row -> candidate index
        int q = qg * 16 + qcol;
#pragma unroll
        for (int r = 0; r < 4; ++r) {
          float dv = (r == 0) ? D.x : (r == 1) ? D.y : (r == 2) ? D.z : D.w;
          if (dv <= Tq) {
            int pos = atomicAdd(&scnt[q], 1);
            if (pos < CAP) survj[q][pos] = (u32)(jb + r);
          }
        }
      }
    }
  }
  __syncthreads();                           // merge survivor lists across halves

  // ---- epilogue: np-exact keys, u64 bitonic top-16, gather z + max ----
  const float* zb = z + (size_t)b * NN * 64;
#pragma unroll 1
  for (int u = 0; u < 8; ++u) {
    int q = w * 8 + u;                       // each wave owns 8 queries
    int n = scnt[q]; if (n > CAP) n = CAP;
    float4 qv = cp4[i0b + q];                // uniform load
    float qxs = rfl(-0.5f * qv.x), qys = rfl(-0.5f * qv.y);
    float qzs = rfl(-0.5f * qv.z), qws = rfl(qv.w);
    u64 v = ~0ull;
    if (lane < n) {
      int j = (int)survj[q][lane];
      float4 cj = cp4[j];
      float de = dist_exact(qxs, qys, qzs, qws,
                            -0.5f * cj.x, -0.5f * cj.y, -0.5f * cj.z, cj.w);
      u32 f = __float_as_uint(de);
      u32 m32 = f ^ ((u32)(((int)f) >> 31) | 0x80000000u);
      v = ((u64)m32 << 32) | (u32)j;
    }
#pragma unroll
    for (int k = 2; k <= 64; k <<= 1) {
#pragma unroll
      for (int jm = k >> 1; jm >= 1; jm >>= 1) {
        u64 o = shfl_xor_u64(v, jm);
        bool keepmin = ((lane & jm) == 0) == ((lane & k) == 0);
        u64 mn = min_u64(v, o);
        u64 mx = (v < o) ? o : v;
        v = keepmin ? mn : mx;
      }
    }
    if (lane < 16) sidx[q][lane] = (int)(v & 0xFFFFFFFFull);
  }
#pragma unroll 1
  for (int u = 0; u < 8; ++u) {
    int q = w * 8 + u;
    const int* id = sidx[q];                 // written by this wave above
    float m = -3.402823466e+38f;
#pragma unroll
    for (int k = 0; k < 16; ++k)
      m = fmaxf(m, zb[(size_t)id[k] * 64 + lane]);   // coalesced 256B row
    ys[lane][q] = m;
  }
  __syncthreads();                           // transpose for coalesced store
#pragma unroll
  for (int r = 0; r < 8; ++r) {
    int e = r * 256 + t;
    int o = e >> 5, qq = e & 31;
    y[((size_t)b * 64 + o) * NN + i0b + qq] = ys[o][qq];
  }
}

extern "C" void kernel_launch(void* const* d_in, const int* in_sizes, int n_in,
                              void* d_out, int out_size, void* d_ws, size_t ws_size,
                              hipStream_t stream) {
  const float* x      = (const float*)d_in[0];   // [B,64,N]
  const float* coords = (const float*)d_in[1];   // [B,3,N]
  const float* W      = (const float*)d_in[2];   // [64,64]
  float* y = (float*)d_out;                      // [B,64,N] then coords

  char* ws = (char*)d_ws;
  float4* c4p = (float4*)ws;                     // 512 KB
  float*  z   = (float*)(ws + (1u << 20));       // 8 MB @ 1MB
  u32*    Ap  = (u32*)(ws + (9u << 20));         // 1 MB bf16 A-plane @ 9MB

  float* ycoords = y + (size_t)BB * 64 * NN;

  fused_prep_zmat<<<1024 + 128, 256, 0, stream>>>(x, W, coords, z, c4p, Ap, ycoords);
  knn_gather<<<BB * NN / 32, 256, 0, stream>>>(c4p, Ap, z, y);
}